// Round 4
// baseline (609.885 us; speedup 1.0000x reference)
//
#include <hip/hip_runtime.h>

#define D_IN 256
#define D_OUT 128

typedef __bf16  bf16x8 __attribute__((ext_vector_type(8)));
typedef float   f32x4  __attribute__((ext_vector_type(4)));

// ---------------- W transpose + bf16: Wt[col][k] = bf16(W[k][col]) ----------------
__global__ __launch_bounds__(256) void wtrans_kernel(const float* __restrict__ W,
                                                     __bf16* __restrict__ Wt) {
    int n = blockIdx.x * 256 + threadIdx.x;       // 32768 elems
    int k = n >> 7;            // 0..255
    int col = n & 127;         // 0..127
    Wt[(size_t)col * D_IN + k] = (__bf16)W[(size_t)k * D_OUT + col];
}

// ---------------- GEMM: h16[M,128] = bf16( x[M,256] @ W[256,128] ) via MFMA ----------------
__global__ __launch_bounds__(256) void gemm_mfma_kernel(const float* __restrict__ x,
                                                        const __bf16* __restrict__ Wt,
                                                        __bf16* __restrict__ h16, int M) {
    const int lane = threadIdx.x & 63;
    const int wid  = threadIdx.x >> 6;
    const int r0   = blockIdx.x * 128 + wid * 32;
    const int lr   = lane & 15;          // row-in-tile for A, col-in-tile for B
    const int koff = (lane >> 4) * 8;    // k offset within 32-k tile

    int rowA = r0 + lr;        if (rowA >= M) rowA = M - 1;
    int rowB = r0 + 16 + lr;   if (rowB >= M) rowB = M - 1;
    const float* pa0 = &x[(size_t)rowA * D_IN + koff];
    const float* pa1 = &x[(size_t)rowB * D_IN + koff];

    f32x4 acc0[8], acc1[8];
#pragma unroll
    for (int c = 0; c < 8; ++c) { acc0[c] = (f32x4)0.f; acc1[c] = (f32x4)0.f; }

#pragma unroll
    for (int t = 0; t < 8; ++t) {
        float4 fa0 = *(const float4*)(pa0 + t * 32);
        float4 fa1 = *(const float4*)(pa0 + t * 32 + 4);
        float4 fb0 = *(const float4*)(pa1 + t * 32);
        float4 fb1 = *(const float4*)(pa1 + t * 32 + 4);
        bf16x8 aA, aB;
        aA[0]=(__bf16)fa0.x; aA[1]=(__bf16)fa0.y; aA[2]=(__bf16)fa0.z; aA[3]=(__bf16)fa0.w;
        aA[4]=(__bf16)fa1.x; aA[5]=(__bf16)fa1.y; aA[6]=(__bf16)fa1.z; aA[7]=(__bf16)fa1.w;
        aB[0]=(__bf16)fb0.x; aB[1]=(__bf16)fb0.y; aB[2]=(__bf16)fb0.z; aB[3]=(__bf16)fb0.w;
        aB[4]=(__bf16)fb1.x; aB[5]=(__bf16)fb1.y; aB[6]=(__bf16)fb1.z; aB[7]=(__bf16)fb1.w;
#pragma unroll
        for (int c = 0; c < 8; ++c) {
            bf16x8 b = *(const bf16x8*)&Wt[(size_t)(c * 16 + lr) * D_IN + t * 32 + koff];
            acc0[c] = __builtin_amdgcn_mfma_f32_16x16x32_bf16(aA, b, acc0[c], 0, 0, 0);
            acc1[c] = __builtin_amdgcn_mfma_f32_16x16x32_bf16(aB, b, acc1[c], 0, 0, 0);
        }
    }

    const int q = lane >> 4;
#pragma unroll
    for (int c = 0; c < 8; ++c) {
        int col = c * 16 + lr;
#pragma unroll
        for (int i = 0; i < 4; ++i) {
            int ra = r0 + q * 4 + i;
            int rb = r0 + 16 + q * 4 + i;
            if (ra < M) h16[(size_t)ra * D_OUT + col] = (__bf16)acc0[c][i];
            if (rb < M) h16[(size_t)rb * D_OUT + col] = (__bf16)acc1[c][i];
        }
    }
}

// ---------------- hist + per-edge rank ----------------
__global__ void hist_kernel(const int* __restrict__ dst, int* __restrict__ count,
                            int* __restrict__ rank, int E) {
    int i = blockIdx.x * blockDim.x + threadIdx.x;
    int stride = gridDim.x * blockDim.x;
    for (; i < E; i += stride) {
        int d = __builtin_nontemporal_load(dst + i);
        int r = atomicAdd(&count[d], 1);
        __builtin_nontemporal_store(r, rank + i);
    }
}

__global__ void scan1_kernel(const int* __restrict__ count, int* __restrict__ offsets,
                             int* __restrict__ bsum, int N) {
    __shared__ int s[256];
    int tid = threadIdx.x;
    int i = blockIdx.x * 256 + tid;
    int v = (i < N) ? count[i] : 0;
    s[tid] = v;
    __syncthreads();
    for (int off = 1; off < 256; off <<= 1) {
        int t = (tid >= off) ? s[tid - off] : 0;
        __syncthreads();
        s[tid] += t;
        __syncthreads();
    }
    if (i < N) offsets[i] = s[tid] - v;
    if (tid == 255) bsum[blockIdx.x] = s[255];
}

__global__ void scan2_kernel(const int* __restrict__ bsum, int* __restrict__ bscan, int NB) {
    __shared__ int s[512];
    int tid = threadIdx.x;
    int v = (tid < NB) ? bsum[tid] : 0;
    s[tid] = v;
    __syncthreads();
    for (int off = 1; off < 512; off <<= 1) {
        int t = (tid >= off) ? s[tid - off] : 0;
        __syncthreads();
        s[tid] += t;
        __syncthreads();
    }
    if (tid < NB) bscan[tid] = s[tid] - v;
}

__global__ void scan3_kernel(int* __restrict__ offsets, const int* __restrict__ bscan, int N) {
    int i = blockIdx.x * blockDim.x + threadIdx.x;
    if (i < N) offsets[i] += bscan[i >> 8];
}

// ---------------- scatter: XCD-partitioned, atomic-free, packed 4B payload ----------------
// payload: (src << 14) | bf16bits(w)   [src < 2^17, w in [0,1] -> bf16 bits < 2^14]
__global__ __launch_bounds__(256) void scatter_kernel(const int* __restrict__ src,
                                                      const int* __restrict__ dst,
                                                      const float* __restrict__ w,
                                                      const int* __restrict__ rank,
                                                      const int* __restrict__ offsets,
                                                      unsigned int* __restrict__ ep,
                                                      int E, int npx, int CS) {
    const int xcd   = blockIdx.x & 7;
    const int chunk = blockIdx.x >> 3;
    const int lo = xcd * npx;
    const int hi = lo + npx;
    const int e1 = min(E, (chunk + 1) * CS);
    for (int i = chunk * CS + threadIdx.x; i < e1; i += 256) {
        int d = __builtin_nontemporal_load(dst + i);
        if (d >= lo && d < hi) {
            int   s  = __builtin_nontemporal_load(src + i);
            float ww = __builtin_nontemporal_load(w + i);
            int   r  = __builtin_nontemporal_load(rank + i);
            __bf16 bw = (__bf16)ww;
            unsigned short wb = __builtin_bit_cast(unsigned short, bw);
            ep[offsets[d] + r] = ((unsigned int)s << 14) | (unsigned int)wb;
        }
    }
}

// ---------------- SpMM: one wave per destination node, 16-deep MLP ----------------
__global__ __launch_bounds__(256) void spmm_kernel(const int* __restrict__ offsets,
                                                   const int* __restrict__ count,
                                                   const unsigned int* __restrict__ ep,
                                                   const unsigned int* __restrict__ h16,
                                                   float* __restrict__ out, int N) {
    int wid  = (blockIdx.x * 256 + threadIdx.x) >> 6;   // node id
    int lane = threadIdx.x & 63;
    if (wid >= N) return;
    int start = offsets[wid];
    int cnt   = count[wid];
    float ax = 0.f, ay = 0.f;
    for (int j = 0; j < cnt; j += 16) {
        unsigned int p[16];
#pragma unroll
        for (int k = 0; k < 16; ++k) {
            int jj = j + k;
            int idx = start + (jj < cnt ? jj : cnt - 1);
            p[k] = __builtin_nontemporal_load(ep + idx);
        }
        unsigned int u[16];
#pragma unroll
        for (int k = 0; k < 16; ++k)
            u[k] = h16[(size_t)(p[k] >> 14) * 64 + lane];
#pragma unroll
        for (int k = 0; k < 16; ++k) {
            int jj = j + k;
            float ww = (jj < cnt) ? __uint_as_float((p[k] & 0x3FFFu) << 16) : 0.f;
            ax += ww * __uint_as_float(u[k] << 16);
            ay += ww * __uint_as_float(u[k] & 0xffff0000u);
        }
    }
    __builtin_nontemporal_store(ax, &out[(size_t)wid * D_OUT + lane * 2 + 0]);
    __builtin_nontemporal_store(ay, &out[(size_t)wid * D_OUT + lane * 2 + 1]);
}

// ---------------- fallback: atomic scatter (if ws too small for CSR) ----------------
__global__ __launch_bounds__(256) void edge_atomic_kernel(const int* __restrict__ src,
                                                          const int* __restrict__ dst,
                                                          const float* __restrict__ w,
                                                          const unsigned int* __restrict__ h16,
                                                          float* __restrict__ out, int E) {
    int wid  = (blockIdx.x * 256 + threadIdx.x) >> 6;
    int lane = threadIdx.x & 63;
    if (wid >= E) return;
    int s = src[wid], d = dst[wid];
    float ww = w[wid];
    unsigned int u = h16[(size_t)s * 64 + lane];
    atomicAdd(&out[(size_t)d * D_OUT + lane * 2 + 0], ww * __uint_as_float(u << 16));
    atomicAdd(&out[(size_t)d * D_OUT + lane * 2 + 1], ww * __uint_as_float(u & 0xffff0000u));
}

extern "C" void kernel_launch(void* const* d_in, const int* in_sizes, int n_in,
                              void* d_out, int out_size, void* d_ws, size_t ws_size,
                              hipStream_t stream) {
    const float* x    = (const float*)d_in[0];
    const float* W    = (const float*)d_in[1];
    const int*   esrc = (const int*)d_in[2];
    const int*   edst = (const int*)d_in[3];
    const float* ew   = (const float*)d_in[4];
    float* out = (float*)d_out;

    const int M = in_sizes[0] / D_IN;   // 100000 nodes
    const int E = in_sizes[2];          // 3200000 edges

    char* ws = (char*)d_ws;
    size_t off = 0;
    __bf16*       h16    = (__bf16*)      (ws + off); off += (size_t)M * D_OUT * 2;  // 25.6 MB
    unsigned int* ep     = (unsigned int*)(ws + off); off += (size_t)E * 4;          // 12.8 MB
    int*          rank   = (int*)         (ws + off); off += (size_t)E * 4;          // 12.8 MB
    __bf16*       Wt     = (__bf16*)      (ws + off); off += (size_t)D_IN * D_OUT * 2;
    int*          offsets= (int*)         (ws + off); off += (size_t)M * 4;
    int*          count  = (int*)         (ws + off); off += (size_t)M * 4;
    int*          bsum   = (int*)         (ws + off); off += 2048;
    int*          bscan  = (int*)         (ws + off); off += 2048;
    // packing needs src indices to fit 17 bits
    const bool use_csr = (off <= ws_size) && (M <= (1 << 17));

    // dense projection (bf16 MFMA)
    wtrans_kernel<<<(D_IN * D_OUT + 255) / 256, 256, 0, stream>>>(W, Wt);
    gemm_mfma_kernel<<<(M + 127) / 128, 256, 0, stream>>>(x, Wt, h16, M);

    if (use_csr) {
        int NB = (M + 255) / 256;   // 391 blocks; scan2 handles up to 512
        hipMemsetAsync(count, 0, (size_t)M * 4, stream);
        hist_kernel  <<<2048, 256, 0, stream>>>(edst, count, rank, E);
        scan1_kernel <<<NB, 256, 0, stream>>>(count, offsets, bsum, M);
        scan2_kernel <<<1, 512, 0, stream>>>(bsum, bscan, NB);
        scan3_kernel <<<NB, 256, 0, stream>>>(offsets, bscan, M);

        const int NCHUNK = 256;
        const int CS  = (E + NCHUNK - 1) / NCHUNK;   // edges per chunk
        const int npx = (M + 7) / 8;                 // nodes per XCD range
        scatter_kernel<<<NCHUNK * 8, 256, 0, stream>>>(esrc, edst, ew, rank, offsets,
                                                       ep, E, npx, CS);
        spmm_kernel  <<<(M + 3) / 4, 256, 0, stream>>>(offsets, count, ep,
                                                       (const unsigned int*)h16, out, M);
    } else {
        hipMemsetAsync(d_out, 0, (size_t)out_size * 4, stream);
        long long nthreads = (long long)E * 64;
        edge_atomic_kernel<<<(nthreads + 255) / 256, 256, 0, stream>>>(
            esrc, edst, ew, (const unsigned int*)h16, out, E);
    }
}